// Round 13
// baseline (86.101 us; speedup 1.0000x reference)
//
#include <hip/hip_runtime.h>

#define NATOMS 13
#define NP (NATOMS * NATOMS)   // 169

constexpr int N_ = 1024;   // rows
constexpr int H_ = 512;    // inner dim
constexpr int O_ = 512;    // output dim
constexpr int RB = 4;      // rows per W stream (quad)
constexpr int OSPLIT = 2;
constexpr int OC = O_ / OSPLIT;        // 256 cols per panel (1KB contiguous)
constexpr int MAXQUAD = 384;           // >= sum ceil(c_g/4) (<=382)
constexpr int NB = MAXQUAD * OSPLIT;   // 768 blocks (div by 8)

// Single fused kernel. Every block redundantly rebuilds the bucket table in
// LDS (deterministic: stable partition by row index), then runs the proven
// R10 quad-GEMV body. No build kernel, no workspace, one launch.
__global__ __launch_bounds__(256)
void fused_gemv(const int* __restrict__ x,
                const int* __restrict__ fact,
                const float* __restrict__ inp,
                const float* __restrict__ params,
                const float* __restrict__ bias,
                const int* __restrict__ msg_to_p,
                const int* __restrict__ order_p,
                float* __restrict__ out, int N) {
    // ---- block mapping: R10's bijective XCD-chunked swizzle (NB % 8 == 0)
    constexpr int q8 = NB / 8;
    const int b = blockIdx.x;
    const int Lg = (b & 7) * q8 + (b >> 3);
    const int quad = Lg >> 1;
    const int op   = Lg & 1;

    const int tid = threadIdx.x;

    __shared__ float  fp_s[H_][RB];      // 8 KB
    __shared__ float4 red[4][RB][64];    // 16 KB — build scratch aliased here
    int* s_id     = (int*)&red[0][0][0];      // [N_]
    int* s_sorted = s_id + N_;                // [N_]
    int* s_cnt    = s_sorted + N_;            // [NP]
    int* s_start  = s_cnt + NP;               // [NP]
    int* s_qstart = s_start + NP;             // [NP+1]  (total 10.2 KB < 16 KB)

    // ---- redundant per-block bucket build (deterministic) ----
    for (int i = tid; i < NP; i += 256) s_cnt[i] = 0;
    __syncthreads();
#pragma unroll
    for (int k = 0; k < N_ / 256; ++k) {
        const int n = k * 256 + tid;
        const int f0 = fact[2 * n];
        const int id = x[f0 * 3 + 1] * NATOMS + x[f0 * 3 + 2];
        s_id[n] = id;
        atomicAdd(&s_cnt[id], 1);
    }
    __syncthreads();
    if (tid == 0) {
        int run = 0, qrun = 0;
        for (int g = 0; g < NP; ++g) {
            s_start[g] = run;   run  += s_cnt[g];
            s_qstart[g] = qrun; qrun += (s_cnt[g] + RB - 1) >> 2;
        }
        s_qstart[NP] = qrun;
    }
    __syncthreads();
    // stable partition: thread g collects its group's rows in row-index order
    if (tid < NP) {
        const int g = tid;
        int c = 0;
        const int st = s_start[g];
        for (int n4 = 0; n4 < N_ / 4; ++n4) {
            const int4 v = ((const int4*)s_id)[n4];   // ordered unpack: stable
            if (v.x == g) s_sorted[st + c++] = 4 * n4 + 0;
            if (v.y == g) s_sorted[st + c++] = 4 * n4 + 1;
            if (v.z == g) s_sorted[st + c++] = 4 * n4 + 2;
            if (v.w == g) s_sorted[st + c++] = 4 * n4 + 3;
        }
    }
    __syncthreads();

    if (quad >= s_qstart[NP]) return;   // uniform exit

    // find this quad's group (uniform binary search over s_qstart)
    int glo = 0, ghi = NP;
    while (ghi - glo > 1) {
        const int gm = (glo + ghi) >> 1;
        if (s_qstart[gm] <= quad) glo = gm; else ghi = gm;
    }
    const int id = glo;                       // group == weight-matrix id
    const int kq = quad - s_qstart[id];       // quad index within group
    const int c  = s_cnt[id];
    const int st = s_start[id];

    const int msg_to = *msg_to_p;
    const int order  = *order_p;
    const int sub = tid >> 6;        // 0..3: h-phase
    const int l   = tid & 63;        // col-quad within 256-col panel
    const int o0  = op * OC;

    // hoist store-row into a register BEFORE red clobbers s_sorted
    const int sidx  = RB * kq + sub;
    const int myrow = (sidx < c) ? s_sorted[st + sidx] : -1;

    // ---- stage fact_prod for the quad's rows (R10 pattern) ----
#pragma unroll
    for (int r = 0; r < RB; ++r) {
        const int idx = RB * kq + r;
        const int row = (idx < c) ? s_sorted[st + idx] : -1;
        if (row >= 0) {
#pragma unroll
            for (int k = 0; k < H_ / 256; ++k) {
                const int h = k * 256 + tid;
                float p = 1.0f;
                for (int i = 0; i < order; ++i)
                    if (i != msg_to)
                        p *= inp[((size_t)i * N + row) * H_ + h];
                fp_s[h][r] = p;
            }
        } else {
#pragma unroll
            for (int k = 0; k < H_ / 256; ++k) fp_s[k * 256 + tid][r] = 0.0f;
        }
    }
    __syncthreads();

    // ---- R10 FMA core: 1 float4 W load + 1 b128 broadcast + 16 FMAs per h
    const float* __restrict__ wbase =
        params + (size_t)id * H_ * O_ + (size_t)sub * O_ + o0 + 4 * l;

    float4 a0 = make_float4(0,0,0,0), a1 = a0, a2 = a0, a3 = a0;

#define FMA4(acc, s, wv) acc.x += (s) * wv.x; acc.y += (s) * wv.y;    \
                         acc.z += (s) * wv.z; acc.w += (s) * wv.w;
#pragma unroll 8
    for (int hh = 0; hh < H_ / 4; ++hh) {
        const float4 w = *(const float4*)(wbase + (size_t)hh * 4 * O_);
        const float4 f = *(const float4*)&fp_s[4 * hh + sub][0];
        FMA4(a0, f.x, w)
        FMA4(a1, f.y, w)
        FMA4(a2, f.z, w)
        FMA4(a3, f.w, w)
    }
#undef FMA4

    __syncthreads();                 // build reads done; safe to clobber red
    red[sub][0][l] = a0;
    red[sub][1][l] = a1;
    red[sub][2][l] = a2;
    red[sub][3][l] = a3;
    __syncthreads();

    if (myrow >= 0) {
        const float4 p0 = red[0][sub][l];
        const float4 p1 = red[1][sub][l];
        const float4 p2 = red[2][sub][l];
        const float4 p3 = red[3][sub][l];
        const float4 bv = *(const float4*)(bias + (size_t)id * O_ + o0 + 4 * l);
        float4 s;
        s.x = p0.x + p1.x + p2.x + p3.x + bv.x;
        s.y = p0.y + p1.y + p2.y + p3.y + bv.y;
        s.z = p0.z + p1.z + p2.z + p3.z + bv.z;
        s.w = p0.w + p1.w + p2.w + p3.w + bv.w;
        *(float4*)(out + (size_t)myrow * O_ + o0 + 4 * l) = s;
    }
}

// ---------------------------------------------------------------------- launch
extern "C" void kernel_launch(void* const* d_in, const int* in_sizes, int n_in,
                              void* d_out, int out_size, void* d_ws, size_t ws_size,
                              hipStream_t stream) {
    const int*   x      = (const int*)d_in[0];
    const int*   fact   = (const int*)d_in[1];
    const float* inp    = (const float*)d_in[2];
    const float* params = (const float*)d_in[3];
    const float* bias   = (const float*)d_in[4];
    const int*   msg_to = (const int*)d_in[5];
    const int*   order  = (const int*)d_in[6];
    float*       out    = (float*)d_out;

    const int N = in_sizes[1] / 2;   // 1024

    hipLaunchKernelGGL(fused_gemv, dim3(NB), dim3(256), 0, stream,
                       x, fact, inp, params, bias, msg_to, order, out, N);
}

// Round 14
// 48.971 us; speedup vs baseline: 1.7582x; 1.7582x over previous
//
#include <hip/hip_runtime.h>

#define NATOMS 13
#define NP (NATOMS * NATOMS)   // 169

constexpr int N_ = 1024;   // rows
constexpr int H_ = 512;    // inner dim
constexpr int O_ = 512;    // output dim
constexpr int RB = 4;      // rows per W stream (quad)
constexpr int OSPLIT = 2;
constexpr int OC = O_ / OSPLIT;        // 256 cols per panel (1KB contiguous)
constexpr int HPH = 8;                 // h-phases = waves per block
constexpr int MAXQUAD = 384;           // >= sum ceil(c_g/4) (<=382)
constexpr int NB = MAXQUAD * OSPLIT;   // 768 blocks (div by 8)
constexpr int RECS = 8;    // ints per quad record: rows[4], id, pad

// ws ints: [0] nquads; records at ws+16: [quad*RECS + {0..3}] rows, [+4] id
// ----------------------------------------------------------------- build quads
// (unchanged from R10 — proven)
__global__ void build_quads(const int* __restrict__ x,
                            const int* __restrict__ fact,
                            int* __restrict__ ws, int N) {
    __shared__ int s_id[N_];
    __shared__ int s_cnt[NP];
    __shared__ int s_start[NP];
    __shared__ int s_qstart[NP];
    __shared__ int s_pos[NP];
    __shared__ int s_sorted[N_];
    const int tid = threadIdx.x, bd = blockDim.x;

    for (int i = tid; i < NP; i += bd) { s_cnt[i] = 0; s_pos[i] = 0; }
    __syncthreads();
    for (int n = tid; n < N; n += bd) {
        const int f0 = fact[2 * n];
        const int id = x[f0 * 3 + 1] * NATOMS + x[f0 * 3 + 2];
        s_id[n] = id;
        atomicAdd(&s_cnt[id], 1);
    }
    __syncthreads();
    if (tid == 0) {
        int run = 0, qrun = 0;
        for (int g = 0; g < NP; ++g) {
            s_start[g] = run;   run  += s_cnt[g];
            s_qstart[g] = qrun; qrun += (s_cnt[g] + RB - 1) / RB;
        }
        ws[0] = qrun;  // nquads
    }
    __syncthreads();
    for (int n = tid; n < N; n += bd) {
        const int id = s_id[n];
        const int p = atomicAdd(&s_pos[id], 1);
        s_sorted[s_start[id] + p] = n;
    }
    __syncthreads();
    for (int g = tid; g < NP; g += bd) {
        const int c = s_cnt[g], st = s_start[g], qs = s_qstart[g];
        const int nq = (c + RB - 1) / RB;
        for (int k = 0; k < nq; ++k) {
            int* rec = ws + 16 + (size_t)(qs + k) * RECS;
            for (int r = 0; r < RB; ++r) {
                const int idx = k * RB + r;
                rec[r] = (idx < c) ? s_sorted[st + idx] : -1;
            }
            rec[RB] = g;
        }
    }
}

// ------------------------------------------------------------------ quad GEMV
// One block per (quad, o-panel), 512 threads = 8 waves. sub=tid>>6 in {0..7}
// is the h-phase (h = 8*hh + sub): the 8 waves stream DISJOINT h-rows of the
// same 512x256 W panel, each as a 1KB-contiguous wave load (R9's proven
// request width, 2x R9's wave concurrency, R10's byte count: 288 MB).
// End: 8-way LDS reduce, bias, direct float4 store. No atomics, no memset.
__global__ __launch_bounds__(512)
void quad_gemv(const int* __restrict__ ws,
               const float* __restrict__ inp,
               const float* __restrict__ params,
               const float* __restrict__ bias,
               const int* __restrict__ msg_to_p,
               const int* __restrict__ order_p,
               float* __restrict__ out, int N) {
    // bijective XCD-chunked swizzle (NB % 8 == 0), unchanged from R10
    constexpr int q8 = NB / 8;
    const int b = blockIdx.x;
    const int Lg = (b & 7) * q8 + (b >> 3);
    const int quad = Lg >> 1;
    const int op   = Lg & 1;

    if (quad >= ws[0]) return;
    const int* rec = ws + 16 + (size_t)quad * RECS;
    const int id = rec[RB];

    const int msg_to = *msg_to_p;
    const int order  = *order_p;
    const int tid = threadIdx.x;
    const int sub = tid >> 6;        // 0..7: h-phase (one wave each)
    const int l   = tid & 63;        // col-quad within 256-col panel
    const int o0  = op * OC;

    __shared__ float  fp_s[H_][RB];        // 8 KB, [h][r]
    __shared__ float4 red[HPH][RB][64];    // 32 KB, [sub][r][l]

    // stage fact_prod: 512 threads -> one h per thread per row, single pass
#pragma unroll
    for (int r = 0; r < RB; ++r) {
        const int row = rec[r];
        float p = 0.0f;
        if (row >= 0) {
            p = 1.0f;
            for (int i = 0; i < order; ++i)
                if (i != msg_to)
                    p *= inp[((size_t)i * N + row) * H_ + tid];
        }
        fp_s[tid][r] = p;
    }
    __syncthreads();

    // h-rows for this sub: h = 8*hh + sub, hh in [0, 64)
    const float* __restrict__ wbase =
        params + (size_t)id * H_ * O_ + (size_t)sub * O_ + o0 + 4 * l;

    float4 a0 = make_float4(0,0,0,0), a1 = a0, a2 = a0, a3 = a0;

#define FMA4(acc, s, wv) acc.x += (s) * wv.x; acc.y += (s) * wv.y;    \
                         acc.z += (s) * wv.z; acc.w += (s) * wv.w;
#pragma unroll 8
    for (int hh = 0; hh < H_ / HPH; ++hh) {
        const float4 w = *(const float4*)(wbase + (size_t)hh * HPH * O_);
        const float4 f = *(const float4*)&fp_s[HPH * hh + sub][0];
        FMA4(a0, f.x, w)
        FMA4(a1, f.y, w)
        FMA4(a2, f.z, w)
        FMA4(a3, f.w, w)
    }
#undef FMA4

    red[sub][0][l] = a0;
    red[sub][1][l] = a1;
    red[sub][2][l] = a2;
    red[sub][3][l] = a3;
    __syncthreads();

    // threads 0..255: thread (r, l2) sums the 8 phase-partials for row rec[r]
    if (tid < RB * 64) {
        const int r  = tid >> 6;
        const int l2 = tid & 63;
        const int row = rec[r];
        if (row >= 0) {
            float4 s = red[0][r][l2];
#pragma unroll
            for (int ss = 1; ss < HPH; ++ss) {
                const float4 p = red[ss][r][l2];
                s.x += p.x; s.y += p.y; s.z += p.z; s.w += p.w;
            }
            const float4 bv = *(const float4*)(bias + (size_t)id * O_ + o0 + 4 * l2);
            s.x += bv.x; s.y += bv.y; s.z += bv.z; s.w += bv.w;
            *(float4*)(out + (size_t)row * O_ + o0 + 4 * l2) = s;
        }
    }
}

// ---------------------------------------------------------------------- launch
extern "C" void kernel_launch(void* const* d_in, const int* in_sizes, int n_in,
                              void* d_out, int out_size, void* d_ws, size_t ws_size,
                              hipStream_t stream) {
    const int*   x      = (const int*)d_in[0];
    const int*   fact   = (const int*)d_in[1];
    const float* inp    = (const float*)d_in[2];
    const float* params = (const float*)d_in[3];
    const float* bias   = (const float*)d_in[4];
    const int*   msg_to = (const int*)d_in[5];
    const int*   order  = (const int*)d_in[6];
    float*       out    = (float*)d_out;

    const int N = in_sizes[1] / 2;   // 1024
    int* ws = (int*)d_ws;

    hipLaunchKernelGGL(build_quads, dim3(1), dim3(256), 0, stream,
                       x, fact, ws, N);

    hipLaunchKernelGGL(quad_gemv, dim3(NB), dim3(512), 0, stream,
                       ws, inp, params, bias, msg_to, order, out, N);
}

// Round 15
// 43.473 us; speedup vs baseline: 1.9806x; 1.1265x over previous
//
#include <hip/hip_runtime.h>

#define NATOMS 13
#define NP (NATOMS * NATOMS)   // 169

constexpr int N_ = 1024;   // rows
constexpr int H_ = 512;    // inner dim
constexpr int O_ = 512;    // output dim
constexpr int RB = 4;      // rows per W stream (quad)
constexpr int OSPLIT = 2;
constexpr int OC = O_ / OSPLIT;        // 256 cols per panel (1KB contiguous)
constexpr int HPH = 8;                 // h-phases = waves per block
constexpr int MAXQUAD = 384;           // >= sum ceil(c_g/4) (<=382)
constexpr int NB = MAXQUAD * OSPLIT;   // 768 blocks (div by 8)
constexpr int RECS = 8;    // ints per quad record: rows[4], id, pad

// ws ints: [0] nquads; records at ws+16: [quad*RECS + {0..3}] rows, [+4] id
// ----------------------------------------------------------------- build quads
// Latency-optimized: 1024 threads (1/row), single-pass histogram + scatter,
// 8-step packed Hillis-Steele scan (lo16: row starts, hi16: quad starts).
__global__ __launch_bounds__(1024)
void build_quads(const int* __restrict__ x,
                 const int* __restrict__ fact,
                 int* __restrict__ ws, int N) {
    __shared__ int s_id[N_];
    __shared__ int s_cnt[NP];
    __shared__ int s_pos[NP];
    __shared__ int s_scan[256];
    __shared__ int s_sorted[N_];
    const int tid = threadIdx.x;

    if (tid < NP) { s_cnt[tid] = 0; s_pos[tid] = 0; }
    __syncthreads();

    // one thread per row: id + histogram (single pass)
    const int f0 = fact[2 * tid];
    const int id = x[f0 * 3 + 1] * NATOMS + x[f0 * 3 + 2];
    s_id[tid] = id;
    atomicAdd(&s_cnt[id], 1);
    __syncthreads();

    // packed inclusive scan over 256 slots (zero beyond NP)
    if (tid < 256) {
        const int c = (tid < NP) ? s_cnt[tid] : 0;
        s_scan[tid] = c | (((c + RB - 1) >> 2) << 16);
    }
    __syncthreads();
#pragma unroll
    for (int off = 1; off < 256; off <<= 1) {
        int nv = 0;
        if (tid < 256) {
            nv = s_scan[tid];
            if (tid >= off) nv += s_scan[tid - off];
        }
        __syncthreads();
        if (tid < 256) s_scan[tid] = nv;
        __syncthreads();
    }
    if (tid == 0) ws[0] = s_scan[NP - 1] >> 16;   // nquads

    // scatter rows into group-sorted order (single pass)
    const int st_me = id ? (s_scan[id - 1] & 0xffff) : 0;
    const int p = atomicAdd(&s_pos[id], 1);
    s_sorted[st_me + p] = tid;
    __syncthreads();

    // emit quad records: one group per thread
    if (tid < NP) {
        const int g  = tid;
        const int c  = s_cnt[g];
        const int st = g ? (s_scan[g - 1] & 0xffff) : 0;
        const int qs = g ? (s_scan[g - 1] >> 16) : 0;
        const int nq = (c + RB - 1) >> 2;
        for (int k = 0; k < nq; ++k) {
            int* rec = ws + 16 + (size_t)(qs + k) * RECS;
#pragma unroll
            for (int r = 0; r < RB; ++r) {
                const int idx = k * RB + r;
                rec[r] = (idx < c) ? s_sorted[st + idx] : -1;
            }
            rec[RB] = g;
        }
    }
}

// ------------------------------------------------------------------ quad GEMV
// Unchanged from R14 (best measured core). One block per (quad, o-panel),
// 512 threads = 8 waves streaming disjoint h-rows of the same 512x256 W
// panel as 1KB-contiguous wave loads. 8-way LDS reduce, direct stores.
__global__ __launch_bounds__(512)
void quad_gemv(const int* __restrict__ ws,
               const float* __restrict__ inp,
               const float* __restrict__ params,
               const float* __restrict__ bias,
               const int* __restrict__ msg_to_p,
               const int* __restrict__ order_p,
               float* __restrict__ out, int N) {
    constexpr int q8 = NB / 8;
    const int b = blockIdx.x;
    const int Lg = (b & 7) * q8 + (b >> 3);
    const int quad = Lg >> 1;
    const int op   = Lg & 1;

    if (quad >= ws[0]) return;
    const int* rec = ws + 16 + (size_t)quad * RECS;
    const int id = rec[RB];

    const int msg_to = *msg_to_p;
    const int order  = *order_p;
    const int tid = threadIdx.x;
    const int sub = tid >> 6;        // 0..7: h-phase (one wave each)
    const int l   = tid & 63;        // col-quad within 256-col panel
    const int o0  = op * OC;

    __shared__ float  fp_s[H_][RB];        // 8 KB, [h][r]
    __shared__ float4 red[HPH][RB][64];    // 32 KB, [sub][r][l]

#pragma unroll
    for (int r = 0; r < RB; ++r) {
        const int row = rec[r];
        float p = 0.0f;
        if (row >= 0) {
            p = 1.0f;
            for (int i = 0; i < order; ++i)
                if (i != msg_to)
                    p *= inp[((size_t)i * N + row) * H_ + tid];
        }
        fp_s[tid][r] = p;
    }
    __syncthreads();

    const float* __restrict__ wbase =
        params + (size_t)id * H_ * O_ + (size_t)sub * O_ + o0 + 4 * l;

    float4 a0 = make_float4(0,0,0,0), a1 = a0, a2 = a0, a3 = a0;

#define FMA4(acc, s, wv) acc.x += (s) * wv.x; acc.y += (s) * wv.y;    \
                         acc.z += (s) * wv.z; acc.w += (s) * wv.w;
#pragma unroll 8
    for (int hh = 0; hh < H_ / HPH; ++hh) {
        const float4 w = *(const float4*)(wbase + (size_t)hh * HPH * O_);
        const float4 f = *(const float4*)&fp_s[HPH * hh + sub][0];
        FMA4(a0, f.x, w)
        FMA4(a1, f.y, w)
        FMA4(a2, f.z, w)
        FMA4(a3, f.w, w)
    }
#undef FMA4

    red[sub][0][l] = a0;
    red[sub][1][l] = a1;
    red[sub][2][l] = a2;
    red[sub][3][l] = a3;
    __syncthreads();

    if (tid < RB * 64) {
        const int r  = tid >> 6;
        const int l2 = tid & 63;
        const int row = rec[r];
        if (row >= 0) {
            float4 s = red[0][r][l2];
#pragma unroll
            for (int ss = 1; ss < HPH; ++ss) {
                const float4 p = red[ss][r][l2];
                s.x += p.x; s.y += p.y; s.z += p.z; s.w += p.w;
            }
            const float4 bv = *(const float4*)(bias + (size_t)id * O_ + o0 + 4 * l2);
            s.x += bv.x; s.y += bv.y; s.z += bv.z; s.w += bv.w;
            *(float4*)(out + (size_t)row * O_ + o0 + 4 * l2) = s;
        }
    }
}

// ---------------------------------------------------------------------- launch
extern "C" void kernel_launch(void* const* d_in, const int* in_sizes, int n_in,
                              void* d_out, int out_size, void* d_ws, size_t ws_size,
                              hipStream_t stream) {
    const int*   x      = (const int*)d_in[0];
    const int*   fact   = (const int*)d_in[1];
    const float* inp    = (const float*)d_in[2];
    const float* params = (const float*)d_in[3];
    const float* bias   = (const float*)d_in[4];
    const int*   msg_to = (const int*)d_in[5];
    const int*   order  = (const int*)d_in[6];
    float*       out    = (float*)d_out;

    const int N = in_sizes[1] / 2;   // 1024
    int* ws = (int*)d_ws;

    hipLaunchKernelGGL(build_quads, dim3(1), dim3(1024), 0, stream,
                       x, fact, ws, N);

    hipLaunchKernelGGL(quad_gemv, dim3(NB), dim3(512), 0, stream,
                       ws, inp, params, bias, msg_to, order, out, N);
}